// Round 2
// baseline (102.407 us; speedup 1.0000x reference)
//
#include <hip/hip_runtime.h>
#include <stdint.h>

// B=4, T=1024, D=64 causal attention probs with deterministic JAX dropout.
// Balanced mirrored-pair decomposition: block g handles rows {4g..4g+3} and
// {1020-4g..1023-4g} -> every block computes ~4096 score dots (uniform work).
#define TT  1024
#define DD  64
#define BB  4
#define NTH 512      // 8 waves
#define GPB 128      // blocks per batch

__device__ __forceinline__ uint32_t rotl32(uint32_t x, int d) {
  return (x << d) | (x >> (32 - d));
}

// JAX partitionable threefry (key(42)) keep-decision at flat index i:
// (o0,o1)=threefry2x32((0,42),(0,i)); bits=o0^o1; u=bitcast((bits>>9)|0x3f800000)-1; keep=u<0.8
__device__ __forceinline__ bool keep_at(uint32_t i) {
  uint32_t x0 = 0u, x1 = i;
  const uint32_t ks0 = 0u, ks1 = 42u;
  const uint32_t ks2 = 0x1BD11BDAu ^ ks0 ^ ks1;
  x0 += ks0; x1 += ks1;
#define R4(a,b,c,d)                              \
  x0 += x1; x1 = rotl32(x1,(a)); x1 ^= x0;       \
  x0 += x1; x1 = rotl32(x1,(b)); x1 ^= x0;       \
  x0 += x1; x1 = rotl32(x1,(c)); x1 ^= x0;       \
  x0 += x1; x1 = rotl32(x1,(d)); x1 ^= x0;
  R4(13,15,26,6)   x0 += ks1; x1 += ks2 + 1u;
  R4(17,29,16,24)  x0 += ks2; x1 += ks0 + 2u;
  R4(13,15,26,6)   x0 += ks0; x1 += ks1 + 3u;
  R4(17,29,16,24)  x0 += ks1; x1 += ks2 + 4u;
  R4(13,15,26,6)   x0 += ks2; x1 += ks0 + 5u;
#undef R4
  const uint32_t bits = x0 ^ x1;
  const float u = __uint_as_float((bits >> 9) | 0x3f800000u) - 1.0f;
  return u < 0.8f;
}

__global__ __launch_bounds__(NTH, 4)
void attn_kernel(const float* __restrict__ Q, const float* __restrict__ K,
                 float* __restrict__ O) {
  __shared__ float redM[8][8];   // [row][wave] partial max
  __shared__ float redS[8][8];   // [row][wave] partial sum

  const int tid = threadIdx.x;
  const int wv  = tid >> 6;
  const int ln  = tid & 63;
  const int g   = blockIdx.x & (GPB - 1);
  const int b   = blockIdx.x / GPB;
  const int lowB  = 4 * g;         // rows lowB..lowB+3
  const int highB = TT - 4 - 4 * g; // rows highB..highB+3  (lowB+3 < highB always)
  const int jmaxL = lowB + 3;
  const int jmaxH = highB + 3;

  // Block-uniform Q pointer -> compiler scalarizes these loads (SGPR operands).
  const float4* Q4 = reinterpret_cast<const float4*>(Q) + (size_t)b * TT * (DD / 4);
  const float4* K4 = reinterpret_cast<const float4*>(K) + (size_t)b * TT * (DD / 4);

  // Each thread owns key columns j = 2*tid, 2*tid+1 for all 8 rows.
  float s[8][2];
#pragma unroll
  for (int r = 0; r < 8; ++r) { s[r][0] = -3.4e38f; s[r][1] = -3.4e38f; }

#pragma unroll
  for (int jj = 0; jj < 2; ++jj) {
    const int j = 2 * tid + jj;
    if (j <= jmaxH) {
      float4 kv[16];                       // k-row j in VGPRs, reused by 8 dots
#pragma unroll
      for (int d = 0; d < 16; ++d) kv[d] = K4[(size_t)j * 16 + d];
      float acc[8] = {0.f, 0.f, 0.f, 0.f, 0.f, 0.f, 0.f, 0.f};
      if (j <= jmaxL) {                    // low-row group (short rows)
#pragma unroll
        for (int d = 0; d < 16; ++d) {
          const float4 k4 = kv[d];
#pragma unroll
          for (int r = 0; r < 4; ++r) {
            const float4 q4 = Q4[(size_t)(lowB + r) * 16 + d];  // uniform -> s_load
            acc[r] = fmaf(q4.x, k4.x, acc[r]);
            acc[r] = fmaf(q4.y, k4.y, acc[r]);
            acc[r] = fmaf(q4.z, k4.z, acc[r]);
            acc[r] = fmaf(q4.w, k4.w, acc[r]);
          }
        }
      }
#pragma unroll
      for (int d = 0; d < 16; ++d) {       // high-row group (always)
        const float4 k4 = kv[d];
#pragma unroll
        for (int r = 0; r < 4; ++r) {
          const float4 q4 = Q4[(size_t)(highB + r) * 16 + d];
          acc[4 + r] = fmaf(q4.x, k4.x, acc[4 + r]);
          acc[4 + r] = fmaf(q4.y, k4.y, acc[4 + r]);
          acc[4 + r] = fmaf(q4.z, k4.z, acc[4 + r]);
          acc[4 + r] = fmaf(q4.w, k4.w, acc[4 + r]);
        }
      }
#pragma unroll
      for (int r = 0; r < 4; ++r) {        // per-row causal validity
        if (j <= lowB + r)  s[r][jj]     = acc[r] * 0.125f;
        if (j <= highB + r) s[4 + r][jj] = acc[4 + r] * 0.125f;
      }
    }
  }

  // ---- row max: wave shuffle reduce, then 8x8 cross-wave reduce in LDS ----
  float pm[8];
#pragma unroll
  for (int r = 0; r < 8; ++r) pm[r] = fmaxf(s[r][0], s[r][1]);
#pragma unroll
  for (int off = 32; off; off >>= 1) {
#pragma unroll
    for (int r = 0; r < 8; ++r) pm[r] = fmaxf(pm[r], __shfl_xor(pm[r], off));
  }
  if (ln == 0) {
#pragma unroll
    for (int r = 0; r < 8; ++r) redM[r][wv] = pm[r];
  }
  __syncthreads();
  float m[8];
#pragma unroll
  for (int r = 0; r < 8; ++r) {
    float mm = redM[r][0];
#pragma unroll
    for (int w = 1; w < 8; ++w) mm = fmaxf(mm, redM[r][w]);  // broadcast reads
    m[r] = mm;
  }

  // ---- exp + row sum (exp(-3.4e38 - m) underflows to 0 for masked lanes) ----
  float ps[8];
#pragma unroll
  for (int r = 0; r < 8; ++r) {
    const float e0 = __expf(s[r][0] - m[r]);
    const float e1 = __expf(s[r][1] - m[r]);
    s[r][0] = e0; s[r][1] = e1;
    ps[r] = e0 + e1;
  }
#pragma unroll
  for (int off = 32; off; off >>= 1) {
#pragma unroll
    for (int r = 0; r < 8; ++r) ps[r] += __shfl_xor(ps[r], off);
  }
  if (ln == 0) {
#pragma unroll
    for (int r = 0; r < 8; ++r) redS[r][wv] = ps[r];
  }
  __syncthreads();
  float rs[8];
#pragma unroll
  for (int r = 0; r < 8; ++r) {
    float ss = 0.f;
#pragma unroll
    for (int w = 0; w < 8; ++w) ss += redS[r][w];
    rs[r] = 1.25f / ss;   // softmax denom + /(1-p) dropout scale
  }

  // ---- write probs with deterministic dropout, float2 coalesced ----
  const int j0 = 2 * tid;
#pragma unroll
  for (int r = 0; r < 8; ++r) {
    const int row = (r < 4) ? (lowB + r) : (highB + r - 4);
    const size_t base = ((size_t)b * TT + row) * TT;
    float v0 = 0.f, v1 = 0.f;
    if (j0 <= row)
      v0 = keep_at((uint32_t)(base + j0)) ? s[r][0] * rs[r] : 0.f;
    if (j0 + 1 <= row)
      v1 = keep_at((uint32_t)(base + j0 + 1)) ? s[r][1] * rs[r] : 0.f;
    float2 o; o.x = v0; o.y = v1;
    *reinterpret_cast<float2*>(O + base + j0) = o;   // zeros clear the poison
  }
}

extern "C" void kernel_launch(void* const* d_in, const int* in_sizes, int n_in,
                              void* d_out, int out_size, void* d_ws, size_t ws_size,
                              hipStream_t stream) {
  const float* q = (const float*)d_in[0];
  const float* k = (const float*)d_in[1];
  float* out = (float*)d_out;
  attn_kernel<<<dim3(BB * GPB), NTH, 0, stream>>>(q, k, out);
}

// Round 4
// 52.542 us; speedup vs baseline: 1.9490x; 1.9490x over previous
//
#include <hip/hip_runtime.h>
#include <hip/hip_fp16.h>
#include <stdint.h>

// B=4, T=1024, D=64 causal attention probs + deterministic JAX dropout.
// Mirror-balanced blocks: block g owns rows {4g..4g+3} and {1020-4g..1023-4g}.
// K rows held as packed f16 in VGPRs (2 j at a time); q as f16 in LDS
// (ds_read_b128 = 8 values); fp32 accumulate via v_fma_mix.
#define TT   1024
#define BB   4
#define NTH  256
#define GPB  128
#define NEG_INF (-3.4e38f)

typedef __fp16 f16x2 __attribute__((ext_vector_type(2)));  // matches cvt_pkrtz
union U32H2 { uint32_t u; f16x2 h; };

__device__ __forceinline__ uint32_t rotl32(uint32_t x, int d) {
  return (x << d) | (x >> (32 - d));
}

// JAX partitionable threefry (key(42)): (o0,o1)=tf2x32((0,42),(0,i));
// bits=o0^o1; u=bitcast((bits>>9)|0x3f800000)-1; keep = u<0.8   [verified R1]
__device__ __forceinline__ bool keep_at(uint32_t i) {
  uint32_t x0 = 0u, x1 = i;
  const uint32_t ks0 = 0u, ks1 = 42u;
  const uint32_t ks2 = 0x1BD11BDAu ^ ks0 ^ ks1;
  x0 += ks0; x1 += ks1;
#define R4(a,b,c,d)                              \
  x0 += x1; x1 = rotl32(x1,(a)); x1 ^= x0;       \
  x0 += x1; x1 = rotl32(x1,(b)); x1 ^= x0;       \
  x0 += x1; x1 = rotl32(x1,(c)); x1 ^= x0;       \
  x0 += x1; x1 = rotl32(x1,(d)); x1 ^= x0;
  R4(13,15,26,6)   x0 += ks1; x1 += ks2 + 1u;
  R4(17,29,16,24)  x0 += ks2; x1 += ks0 + 2u;
  R4(13,15,26,6)   x0 += ks0; x1 += ks1 + 3u;
  R4(17,29,16,24)  x0 += ks1; x1 += ks2 + 4u;
  R4(13,15,26,6)   x0 += ks2; x1 += ks0 + 5u;
#undef R4
  const uint32_t bits = x0 ^ x1;
  const float u = __uint_as_float((bits >> 9) | 0x3f800000u) - 1.0f;
  return u < 0.8f;
}

__device__ __forceinline__ uint32_t pack2(float x, float y) {
  U32H2 t; t.h = __builtin_amdgcn_cvt_pkrtz(x, y);
  return t.u;
}

// acc += dot(q_half2, k_half2) in fp32 (fpext f16 -> v_fma_mix_f32)
__device__ __forceinline__ void fmix2(float& a, uint32_t q, uint32_t k) {
  U32H2 qu, ku; qu.u = q; ku.u = k;
  a = fmaf((float)qu.h[0], (float)ku.h[0], a);
  a = fmaf((float)qu.h[1], (float)ku.h[1], a);
}

__global__ __launch_bounds__(NTH)
void attn_kernel(const float* __restrict__ Q, const float* __restrict__ K,
                 float* __restrict__ O) {
  __shared__ uint32_t qh[8][32];      // 8 rows x 64 d as packed f16 (1 KB)
  __shared__ float redM[8][4], redS[8][4];

  const int tid = threadIdx.x;
  const int wv  = tid >> 6, ln = tid & 63;
  const int g   = blockIdx.x & (GPB - 1);
  const int b   = blockIdx.x >> 7;
  const int lowB  = 4 * g;             // rows lowB..lowB+3   (<= 511)
  const int highB = TT - 4 - 4 * g;    // rows highB..highB+3 (>= 512)
  const int jmaxL = lowB + 3;
  const int jmaxH = highB + 3;

  // ---- stage q (8 rows x 64) as packed f16 into LDS: 256 half2 slots ----
  {
    const int row = tid >> 5, d2 = tid & 31;
    const int rIdx = (row < 4) ? (lowB + row) : (highB + row - 4);
    const float2 qf =
        *reinterpret_cast<const float2*>(Q + ((size_t)(b * TT + rIdx)) * 64 + 2 * d2);
    qh[row][d2] = pack2(qf.x, qf.y);
  }
  __syncthreads();

  const float4* K4 = reinterpret_cast<const float4*>(K) + (size_t)b * TT * 16;
  const float scale = 0.125f;   // 64^-0.5

  float sc[8][4];               // [rowSlot][i], i <-> j = tid + 256*i
#pragma unroll
  for (int r = 0; r < 8; ++r)
#pragma unroll
    for (int i = 0; i < 4; ++i) sc[r][i] = NEG_INF;

  uint32_t kvh[2][32];          // 2 key rows as packed f16 (64 VGPRs)

#define LOADK(JJ, J)                                             \
  { const float4* kb = K4 + (size_t)(J) * 16;                    \
    _Pragma("unroll")                                            \
    for (int d4 = 0; d4 < 16; ++d4) {                            \
      const float4 kf = kb[d4];                                  \
      kvh[JJ][2 * d4]     = pack2(kf.x, kf.y);                   \
      kvh[JJ][2 * d4 + 1] = pack2(kf.z, kf.w);                   \
    } }

#define DOT4(ACC, ROWBASE)                                       \
  _Pragma("unroll")                                              \
  for (int d8 = 0; d8 < 8; ++d8) {                               \
    _Pragma("unroll")                                            \
    for (int r = 0; r < 4; ++r) {                                \
      const uint4 qw =                                           \
          *reinterpret_cast<const uint4*>(&qh[(ROWBASE) + r][d8 * 4]); \
      const uint32_t qa[4] = {qw.x, qw.y, qw.z, qw.w};           \
      _Pragma("unroll")                                          \
      for (int h = 0; h < 4; ++h) {                              \
        fmix2(ACC[0][r], qa[h], kvh[0][d8 * 4 + h]);             \
        fmix2(ACC[1][r], qa[h], kvh[1][d8 * 4 + h]);             \
      }                                                          \
    }                                                            \
  }

  // ================= pair 0: j0 = tid, j1 = tid + 256 (j <= 511) =========
  {
    LOADK(0, tid)
    LOADK(1, tid + 256)
    float accH[2][4] = {{0.f,0.f,0.f,0.f},{0.f,0.f,0.f,0.f}};
    DOT4(accH, 4)                       // high rows: j<=511 < 512 <= row: always valid
#pragma unroll
    for (int r = 0; r < 4; ++r) {
      sc[4 + r][0] = accH[0][r] * scale;
      sc[4 + r][1] = accH[1][r] * scale;
    }
    if (tid <= jmaxL) {                 // low rows need j <= lowB+3
      float accL[2][4] = {{0.f,0.f,0.f,0.f},{0.f,0.f,0.f,0.f}};
      DOT4(accL, 0)
#pragma unroll
      for (int r = 0; r < 4; ++r) {
        if (tid <= lowB + r)       sc[r][0] = accL[0][r] * scale;
        if (tid + 256 <= lowB + r) sc[r][1] = accL[1][r] * scale;
      }
    }
  }
  // ================= pair 1: j2 = tid+512, j3 = tid+768 (high rows only) ==
  if (tid + 512 <= jmaxH) {
    LOADK(0, tid + 512)
    LOADK(1, tid + 768)
    float accH[2][4] = {{0.f,0.f,0.f,0.f},{0.f,0.f,0.f,0.f}};
    DOT4(accH, 4)
#pragma unroll
    for (int r = 0; r < 4; ++r) {
      if (tid + 512 <= highB + r) sc[4 + r][2] = accH[0][r] * scale;
      if (tid + 768 <= highB + r) sc[4 + r][3] = accH[1][r] * scale;
    }
  }

  // ======================= softmax: row max ==============================
  float pm[8];
#pragma unroll
  for (int r = 0; r < 8; ++r)
    pm[r] = fmaxf(fmaxf(sc[r][0], sc[r][1]), fmaxf(sc[r][2], sc[r][3]));
#pragma unroll
  for (int off = 32; off; off >>= 1)
#pragma unroll
    for (int r = 0; r < 8; ++r) pm[r] = fmaxf(pm[r], __shfl_xor(pm[r], off));
  if (ln == 0) {
#pragma unroll
    for (int r = 0; r < 8; ++r) redM[r][wv] = pm[r];
  }
  __syncthreads();
  float m[8];
#pragma unroll
  for (int r = 0; r < 8; ++r)
    m[r] = fmaxf(fmaxf(redM[r][0], redM[r][1]), fmaxf(redM[r][2], redM[r][3]));

  // ======================= exp + row sum =================================
  float ps[8];
#pragma unroll
  for (int r = 0; r < 8; ++r) {
    float s0 = 0.f;
#pragma unroll
    for (int i = 0; i < 4; ++i) {
      const float e = __expf(sc[r][i] - m[r]);   // exp(-inf) -> 0 for masked
      sc[r][i] = e;
      s0 += e;
    }
    ps[r] = s0;
  }
#pragma unroll
  for (int off = 32; off; off >>= 1)
#pragma unroll
    for (int r = 0; r < 8; ++r) ps[r] += __shfl_xor(ps[r], off);
  if (ln == 0) {
#pragma unroll
    for (int r = 0; r < 8; ++r) redS[r][wv] = ps[r];
  }
  __syncthreads();
  float rs[8];
#pragma unroll
  for (int r = 0; r < 8; ++r)
    rs[r] = 1.25f / (redS[r][0] + redS[r][1] + redS[r][2] + redS[r][3]);

  // ============ write probs with deterministic dropout, coalesced ========
#pragma unroll
  for (int r = 0; r < 8; ++r) {
    const int row = (r < 4) ? (lowB + r) : (highB + r - 4);
    const float scv = rs[r];
    const size_t base = ((size_t)b * TT + row) * TT;
#pragma unroll
    for (int i = 0; i < 4; ++i) {
      const int j = tid + 256 * i;
      float v = 0.f;
      if (j <= row)
        v = keep_at((uint32_t)(base + j)) ? sc[r][i] * scv : 0.f;
      O[base + j] = v;                 // zeros clear the poison
    }
  }
#undef LOADK
#undef DOT4
}

extern "C" void kernel_launch(void* const* d_in, const int* in_sizes, int n_in,
                              void* d_out, int out_size, void* d_ws, size_t ws_size,
                              hipStream_t stream) {
  const float* q = (const float*)d_in[0];
  const float* k = (const float*)d_in[1];
  float* out = (float*)d_out;
  attn_kernel<<<dim3(BB * GPB), NTH, 0, stream>>>(q, k, out);
}

// Round 5
// 51.495 us; speedup vs baseline: 1.9887x; 1.0204x over previous
//
#include <hip/hip_runtime.h>
#include <hip/hip_fp16.h>
#include <stdint.h>

// B=4, T=1024, D=64 causal attention probs + deterministic JAX dropout.
// Two kernels: (1) convert Q,K fp32 -> packed f16 in d_ws; (2) mirror-balanced
// attention: block g owns rows {4g..4g+3} and {1020-4g..1023-4g}; K rows load
// directly as packed-f16 uint4 into VGPRs (no fp32 staging -> no spill).
#define TT   1024
#define BB   4
#define NTH  256
#define GPB  128
#define NEG_INF (-3.4e38f)
#define QH_U32 (BB * TT * 32)   // 131072 u32 = Q as half2; Kh follows at same size

typedef __fp16 f16x2 __attribute__((ext_vector_type(2)));
union U32H2 { uint32_t u; f16x2 h; };

__device__ __forceinline__ uint32_t rotl32(uint32_t x, int d) {
  return (x << d) | (x >> (32 - d));
}

// JAX partitionable threefry (key(42)): (o0,o1)=tf2x32((0,42),(0,i));
// bits=o0^o1; u=bitcast((bits>>9)|0x3f800000)-1; keep = u<0.8   [verified R1]
__device__ __forceinline__ bool keep_at(uint32_t i) {
  uint32_t x0 = 0u, x1 = i;
  const uint32_t ks0 = 0u, ks1 = 42u;
  const uint32_t ks2 = 0x1BD11BDAu ^ ks0 ^ ks1;
  x0 += ks0; x1 += ks1;
#define R4(a,b,c,d)                              \
  x0 += x1; x1 = rotl32(x1,(a)); x1 ^= x0;       \
  x0 += x1; x1 = rotl32(x1,(b)); x1 ^= x0;       \
  x0 += x1; x1 = rotl32(x1,(c)); x1 ^= x0;       \
  x0 += x1; x1 = rotl32(x1,(d)); x1 ^= x0;
  R4(13,15,26,6)   x0 += ks1; x1 += ks2 + 1u;
  R4(17,29,16,24)  x0 += ks2; x1 += ks0 + 2u;
  R4(13,15,26,6)   x0 += ks0; x1 += ks1 + 3u;
  R4(17,29,16,24)  x0 += ks1; x1 += ks2 + 4u;
  R4(13,15,26,6)   x0 += ks2; x1 += ks0 + 5u;
#undef R4
  const uint32_t bits = x0 ^ x1;
  const float u = __uint_as_float((bits >> 9) | 0x3f800000u) - 1.0f;
  return u < 0.8f;
}

__device__ __forceinline__ uint32_t pack2(float x, float y) {
  U32H2 t; t.h = __builtin_amdgcn_cvt_pkrtz(x, y);
  return t.u;
}

// acc += dot(q_half2, k_half2) in fp32 (fpext f16 -> v_fma_mix_f32)
__device__ __forceinline__ void fmix2(float& a, uint32_t q, uint32_t k) {
  U32H2 qu, ku; qu.u = q; ku.u = k;
  a = fmaf((float)qu.h[0], (float)ku.h[0], a);
  a = fmaf((float)qu.h[1], (float)ku.h[1], a);
}

// ---- pre-pass: fp32 -> packed f16 for Q and K (1 MB into d_ws) ----
__global__ __launch_bounds__(NTH)
void cvt_kernel(const float* __restrict__ Q, const float* __restrict__ K,
                uint32_t* __restrict__ W) {
  const int i = blockIdx.x * NTH + threadIdx.x;          // 0..131071
  const float2 qf = reinterpret_cast<const float2*>(Q)[i];
  W[i] = pack2(qf.x, qf.y);
  const float2 kf = reinterpret_cast<const float2*>(K)[i];
  W[QH_U32 + i] = pack2(kf.x, kf.y);
}

__global__ __launch_bounds__(NTH)
void attn_kernel(const uint32_t* __restrict__ W, float* __restrict__ O) {
  __shared__ uint32_t qh[8][32];      // 8 rows x 64 d as packed f16 (1 KB)
  __shared__ float redM[8][4], redS[8][4];

  const int tid = threadIdx.x;
  const int wv  = tid >> 6, ln = tid & 63;
  const int g   = blockIdx.x & (GPB - 1);
  const int b   = blockIdx.x >> 7;
  const int lowB  = 4 * g;             // rows lowB..lowB+3   (<= 511)
  const int highB = TT - 4 - 4 * g;    // rows highB..highB+3 (>= 512)
  const int jmaxL = lowB + 3;
  const int jmaxH = highB + 3;

  const uint32_t* Qh = W + (size_t)b * TT * 32;
  const uint4*    K4 = reinterpret_cast<const uint4*>(W + QH_U32) + (size_t)b * TT * 8;

  // ---- stage q (8 rows x 32 u32) into LDS ----
  {
    const int row = tid >> 5, d2 = tid & 31;
    const int rIdx = (row < 4) ? (lowB + row) : (highB + row - 4);
    qh[row][d2] = Qh[(size_t)rIdx * 32 + d2];
  }
  __syncthreads();

  const float scale = 0.125f;   // 64^-0.5

  float sc[8][4];               // [rowSlot][i], i <-> j = tid + 256*i
#pragma unroll
  for (int r = 0; r < 8; ++r)
#pragma unroll
    for (int i = 0; i < 4; ++i) sc[r][i] = NEG_INF;

  uint32_t kvh[2][32];          // 2 key rows as packed f16 (64 VGPRs)

#define LOADK(JJ, J)                                               \
  { const uint4* kb = K4 + (size_t)(J) * 8;                        \
    _Pragma("unroll")                                              \
    for (int d4 = 0; d4 < 8; ++d4)                                 \
      *reinterpret_cast<uint4*>(&kvh[JJ][4 * d4]) = kb[d4];        \
  }

#define DOT4(ACC, ROWBASE)                                       \
  _Pragma("unroll")                                              \
  for (int d8 = 0; d8 < 8; ++d8) {                               \
    _Pragma("unroll")                                            \
    for (int r = 0; r < 4; ++r) {                                \
      const uint4 qw =                                           \
          *reinterpret_cast<const uint4*>(&qh[(ROWBASE) + r][d8 * 4]); \
      const uint32_t qa[4] = {qw.x, qw.y, qw.z, qw.w};           \
      _Pragma("unroll")                                          \
      for (int h = 0; h < 4; ++h) {                              \
        fmix2(ACC[0][r], qa[h], kvh[0][d8 * 4 + h]);             \
        fmix2(ACC[1][r], qa[h], kvh[1][d8 * 4 + h]);             \
      }                                                          \
    }                                                            \
  }

  // ================= pair 0: j0 = tid, j1 = tid + 256 (j <= 511) =========
  {
    LOADK(0, tid)
    LOADK(1, tid + 256)
    float accH[2][4] = {{0.f,0.f,0.f,0.f},{0.f,0.f,0.f,0.f}};
    DOT4(accH, 4)                       // high rows: j<=511 < 512 <= row: valid
#pragma unroll
    for (int r = 0; r < 4; ++r) {
      sc[4 + r][0] = accH[0][r] * scale;
      sc[4 + r][1] = accH[1][r] * scale;
    }
    if (tid <= jmaxL) {                 // low rows need j <= lowB+3
      float accL[2][4] = {{0.f,0.f,0.f,0.f},{0.f,0.f,0.f,0.f}};
      DOT4(accL, 0)
#pragma unroll
      for (int r = 0; r < 4; ++r) {
        if (tid <= lowB + r)       sc[r][0] = accL[0][r] * scale;
        if (tid + 256 <= lowB + r) sc[r][1] = accL[1][r] * scale;
      }
    }
  }
  // ================= pair 1: j2 = tid+512, j3 = tid+768 (high rows only) ==
  if (tid + 512 <= jmaxH) {
    LOADK(0, tid + 512)
    LOADK(1, tid + 768)
    float accH[2][4] = {{0.f,0.f,0.f,0.f},{0.f,0.f,0.f,0.f}};
    DOT4(accH, 4)
#pragma unroll
    for (int r = 0; r < 4; ++r) {
      if (tid + 512 <= highB + r) sc[4 + r][2] = accH[0][r] * scale;
      if (tid + 768 <= highB + r) sc[4 + r][3] = accH[1][r] * scale;
    }
  }

  // ======================= softmax: row max ==============================
  float pm[8];
#pragma unroll
  for (int r = 0; r < 8; ++r)
    pm[r] = fmaxf(fmaxf(sc[r][0], sc[r][1]), fmaxf(sc[r][2], sc[r][3]));
#pragma unroll
  for (int off = 32; off; off >>= 1)
#pragma unroll
    for (int r = 0; r < 8; ++r) pm[r] = fmaxf(pm[r], __shfl_xor(pm[r], off));
  if (ln == 0) {
#pragma unroll
    for (int r = 0; r < 8; ++r) redM[r][wv] = pm[r];
  }
  __syncthreads();
  float m[8];
#pragma unroll
  for (int r = 0; r < 8; ++r)
    m[r] = fmaxf(fmaxf(redM[r][0], redM[r][1]), fmaxf(redM[r][2], redM[r][3]));

  // ======================= exp + row sum =================================
  float ps[8];
#pragma unroll
  for (int r = 0; r < 8; ++r) {
    float s0 = 0.f;
#pragma unroll
    for (int i = 0; i < 4; ++i) {
      const float e = __expf(sc[r][i] - m[r]);   // exp(-inf) -> 0 for masked
      sc[r][i] = e;
      s0 += e;
    }
    ps[r] = s0;
  }
#pragma unroll
  for (int off = 32; off; off >>= 1)
#pragma unroll
    for (int r = 0; r < 8; ++r) ps[r] += __shfl_xor(ps[r], off);
  if (ln == 0) {
#pragma unroll
    for (int r = 0; r < 8; ++r) redS[r][wv] = ps[r];
  }
  __syncthreads();
  float rs[8];
#pragma unroll
  for (int r = 0; r < 8; ++r)
    rs[r] = 1.25f / (redS[r][0] + redS[r][1] + redS[r][2] + redS[r][3]);

  // ============ write probs with deterministic dropout, coalesced ========
#pragma unroll
  for (int r = 0; r < 8; ++r) {
    const int row = (r < 4) ? (lowB + r) : (highB + r - 4);
    const float scv = rs[r];
    const size_t base = ((size_t)b * TT + row) * TT;
#pragma unroll
    for (int i = 0; i < 4; ++i) {
      const int j = tid + 256 * i;
      float v = 0.f;
      if (j <= row)
        v = keep_at((uint32_t)(base + j)) ? sc[r][i] * scv : 0.f;
      O[base + j] = v;                 // zeros clear the poison
    }
  }
#undef LOADK
#undef DOT4
}

extern "C" void kernel_launch(void* const* d_in, const int* in_sizes, int n_in,
                              void* d_out, int out_size, void* d_ws, size_t ws_size,
                              hipStream_t stream) {
  const float* q = (const float*)d_in[0];
  const float* k = (const float*)d_in[1];
  float* out = (float*)d_out;
  uint32_t* w = (uint32_t*)d_ws;      // needs 2*QH_U32*4 = 1 MB
  cvt_kernel<<<dim3(QH_U32 / NTH), NTH, 0, stream>>>(q, k, w);
  attn_kernel<<<dim3(BB * GPB), NTH, 0, stream>>>(w, out);
}

// Round 6
// 40.094 us; speedup vs baseline: 2.5542x; 1.2843x over previous
//
#include <hip/hip_runtime.h>
#include <hip/hip_fp16.h>
#include <stdint.h>

// B=4, T=1024, D=64 causal attention probs + deterministic JAX dropout.
// cvt pre-pass: Q,K fp32 -> packed f16 in d_ws.
// attn: block g owns mirror row pair {g, 1023-g} (1025 dots/block, uniform).
// q rows are block-uniform -> SGPRs (s_load), K row streams through 32 VGPRs.
#define TT   1024
#define BB   4
#define NTH  256
#define NEG_INF (-3.4e38f)
#define QH_U32 (BB * TT * 32)   // Q as half2 words; Kh follows at same size

typedef __fp16 f16x2 __attribute__((ext_vector_type(2)));
union U32H2 { uint32_t u; f16x2 h; };

__device__ __forceinline__ uint32_t rotl32(uint32_t x, int d) {
  return (x << d) | (x >> (32 - d));
}

// JAX partitionable threefry (key(42)): (o0,o1)=tf2x32((0,42),(0,i));
// bits=o0^o1; u=bitcast((bits>>9)|0x3f800000)-1; keep = u<0.8   [verified R1]
__device__ __forceinline__ bool keep_at(uint32_t i) {
  uint32_t x0 = 0u, x1 = i;
  const uint32_t ks0 = 0u, ks1 = 42u;
  const uint32_t ks2 = 0x1BD11BDAu ^ ks0 ^ ks1;
  x0 += ks0; x1 += ks1;
#define R4(a,b,c,d)                              \
  x0 += x1; x1 = rotl32(x1,(a)); x1 ^= x0;       \
  x0 += x1; x1 = rotl32(x1,(b)); x1 ^= x0;       \
  x0 += x1; x1 = rotl32(x1,(c)); x1 ^= x0;       \
  x0 += x1; x1 = rotl32(x1,(d)); x1 ^= x0;
  R4(13,15,26,6)   x0 += ks1; x1 += ks2 + 1u;
  R4(17,29,16,24)  x0 += ks2; x1 += ks0 + 2u;
  R4(13,15,26,6)   x0 += ks0; x1 += ks1 + 3u;
  R4(17,29,16,24)  x0 += ks1; x1 += ks2 + 4u;
  R4(13,15,26,6)   x0 += ks2; x1 += ks0 + 5u;
#undef R4
  const uint32_t bits = x0 ^ x1;
  const float u = __uint_as_float((bits >> 9) | 0x3f800000u) - 1.0f;
  return u < 0.8f;
}

__device__ __forceinline__ uint32_t pack2(float x, float y) {
  U32H2 t; t.h = __builtin_amdgcn_cvt_pkrtz(x, y);
  return t.u;
}

// acc += dot(q_half2, k_half2) in fp32 (fpext f16 -> v_fma_mix_f32)
__device__ __forceinline__ void fmix2(float& a, uint32_t q, uint32_t k) {
  U32H2 qu, ku; qu.u = q; ku.u = k;
  a = fmaf((float)qu.h[0], (float)ku.h[0], a);
  a = fmaf((float)qu.h[1], (float)ku.h[1], a);
}

// ---- pre-pass: fp32 -> packed f16 for Q and K (1 MB into d_ws) ----
__global__ __launch_bounds__(NTH)
void cvt_kernel(const float* __restrict__ Q, const float* __restrict__ K,
                uint32_t* __restrict__ W) {
  const int i = blockIdx.x * NTH + threadIdx.x;          // 0..131071
  const float2 qf = reinterpret_cast<const float2*>(Q)[i];
  W[i] = pack2(qf.x, qf.y);
  const float2 kf = reinterpret_cast<const float2*>(K)[i];
  W[QH_U32 + i] = pack2(kf.x, kf.y);
}

__global__ __launch_bounds__(NTH)
void attn_kernel(const uint32_t* __restrict__ W, float* __restrict__ O) {
  __shared__ float redM[2][4], redS[2][4];

  const int tid = threadIdx.x;
  const int wv  = tid >> 6, ln = tid & 63;
  const int g   = blockIdx.x & 511;
  const int b   = blockIdx.x >> 9;
  const int rowL = g;            // 0..511
  const int rowH = 1023 - g;     // 512..1023

  // ---- q rows: block-uniform loads -> SGPRs (64 scalar regs) ----
  const uint32_t* Qb = W + (size_t)b * (TT * 32);
  uint32_t qL[32], qH[32];
#pragma unroll
  for (int d = 0; d < 32; ++d) {
    qL[d] = Qb[(size_t)rowL * 32 + d];
    qH[d] = Qb[(size_t)rowH * 32 + d];
  }

  const uint4* K4 = reinterpret_cast<const uint4*>(W + QH_U32) + (size_t)b * TT * 8;
  const float scale = 0.125f;   // 64^-0.5

  // sc[0][i] -> rowL, sc[1][i] -> rowH at key j = tid + 256*i
  float sc[2][4];
#pragma unroll
  for (int i = 0; i < 4; ++i) { sc[0][i] = NEG_INF; sc[1][i] = NEG_INF; }

#pragma unroll
  for (int i = 0; i < 4; ++i) {
    const int j = tid + 256 * i;
    if (j <= rowH) {                       // whole-wave skip when 256*i > rowH
      uint32_t kv[32];
      const uint4* kb = K4 + (size_t)j * 8;
#pragma unroll
      for (int d4 = 0; d4 < 8; ++d4)
        *reinterpret_cast<uint4*>(&kv[4 * d4]) = kb[d4];
      float aH = 0.f;
#pragma unroll
      for (int d = 0; d < 32; ++d) fmix2(aH, qH[d], kv[d]);
      sc[1][i] = aH * scale;
      if (j <= rowL) {
        float aL = 0.f;
#pragma unroll
        for (int d = 0; d < 32; ++d) fmix2(aL, qL[d], kv[d]);
        sc[0][i] = aL * scale;
      }
    }
  }

  // ======================= softmax: row max ==============================
  float pm[2];
#pragma unroll
  for (int r = 0; r < 2; ++r)
    pm[r] = fmaxf(fmaxf(sc[r][0], sc[r][1]), fmaxf(sc[r][2], sc[r][3]));
#pragma unroll
  for (int off = 32; off; off >>= 1)
#pragma unroll
    for (int r = 0; r < 2; ++r) pm[r] = fmaxf(pm[r], __shfl_xor(pm[r], off));
  if (ln == 0) { redM[0][wv] = pm[0]; redM[1][wv] = pm[1]; }
  __syncthreads();
  float m[2];
#pragma unroll
  for (int r = 0; r < 2; ++r)
    m[r] = fmaxf(fmaxf(redM[r][0], redM[r][1]), fmaxf(redM[r][2], redM[r][3]));

  // ======================= exp + row sum =================================
  float ps[2];
#pragma unroll
  for (int r = 0; r < 2; ++r) {
    float s0 = 0.f;
#pragma unroll
    for (int i = 0; i < 4; ++i) {
      const float e = __expf(sc[r][i] - m[r]);   // exp(-inf) -> 0 for masked
      sc[r][i] = e;
      s0 += e;
    }
    ps[r] = s0;
  }
#pragma unroll
  for (int off = 32; off; off >>= 1)
#pragma unroll
    for (int r = 0; r < 2; ++r) ps[r] += __shfl_xor(ps[r], off);
  if (ln == 0) { redS[0][wv] = ps[0]; redS[1][wv] = ps[1]; }
  __syncthreads();
  float rs[2];
#pragma unroll
  for (int r = 0; r < 2; ++r)
    rs[r] = 1.25f / (redS[r][0] + redS[r][1] + redS[r][2] + redS[r][3]);

  // ============ write probs with deterministic dropout, coalesced ========
#pragma unroll
  for (int r = 0; r < 2; ++r) {
    const int row = (r == 0) ? rowL : rowH;
    const float scv = rs[r];
    const size_t base = ((size_t)b * TT + row) * TT;
#pragma unroll
    for (int i = 0; i < 4; ++i) {
      const int j = tid + 256 * i;
      float v = 0.f;
      if (j <= row)
        v = keep_at((uint32_t)(base + j)) ? sc[r][i] * scv : 0.f;
      O[base + j] = v;                 // zeros clear the poison
    }
  }
}

extern "C" void kernel_launch(void* const* d_in, const int* in_sizes, int n_in,
                              void* d_out, int out_size, void* d_ws, size_t ws_size,
                              hipStream_t stream) {
  const float* q = (const float*)d_in[0];
  const float* k = (const float*)d_in[1];
  float* out = (float*)d_out;
  uint32_t* w = (uint32_t*)d_ws;      // needs 2*QH_U32*4 = 1 MB
  cvt_kernel<<<dim3(QH_U32 / NTH), NTH, 0, stream>>>(q, k, w);
  attn_kernel<<<dim3(BB * 512), NTH, 0, stream>>>(w, out);
}

// Round 7
// 39.897 us; speedup vs baseline: 2.5668x; 1.0050x over previous
//
#include <hip/hip_runtime.h>
#include <hip/hip_fp16.h>
#include <stdint.h>

// B=4, T=1024, D=64 causal attention probs + deterministic JAX dropout.
// cvt pre-pass: Q,K fp32 -> packed f16 in d_ws.
// attn: block g owns mirror row pair {g, 1023-g} (1025 dots/block, uniform).
// q rows forced to SGPRs (readfirstlane); K rows stream through VGPRs with
// 2-deep prefetch; dots via v_dot2_f32_f16 (4 accumulators).
#define TT   1024
#define BB   4
#define NTH  256
#define NEG_INF (-3.4e38f)
#define QH_U32 (BB * TT * 32)   // Q as half2 words; Kh follows at same size

typedef __fp16 f16x2 __attribute__((ext_vector_type(2)));
union U32H2 { uint32_t u; f16x2 h; };

__device__ __forceinline__ uint32_t rotl32(uint32_t x, int d) {
  return (x << d) | (x >> (32 - d));
}

// JAX partitionable threefry (key(42)): (o0,o1)=tf2x32((0,42),(0,i));
// bits=o0^o1; u=bitcast((bits>>9)|0x3f800000)-1; keep = u<0.8   [verified R1]
__device__ __forceinline__ bool keep_at(uint32_t i) {
  uint32_t x0 = 0u, x1 = i;
  const uint32_t ks0 = 0u, ks1 = 42u;
  const uint32_t ks2 = 0x1BD11BDAu ^ ks0 ^ ks1;
  x0 += ks0; x1 += ks1;
#define R4(a,b,c,d)                              \
  x0 += x1; x1 = rotl32(x1,(a)); x1 ^= x0;       \
  x0 += x1; x1 = rotl32(x1,(b)); x1 ^= x0;       \
  x0 += x1; x1 = rotl32(x1,(c)); x1 ^= x0;       \
  x0 += x1; x1 = rotl32(x1,(d)); x1 ^= x0;
  R4(13,15,26,6)   x0 += ks1; x1 += ks2 + 1u;
  R4(17,29,16,24)  x0 += ks2; x1 += ks0 + 2u;
  R4(13,15,26,6)   x0 += ks0; x1 += ks1 + 3u;
  R4(17,29,16,24)  x0 += ks1; x1 += ks2 + 4u;
  R4(13,15,26,6)   x0 += ks2; x1 += ks0 + 5u;
#undef R4
  const uint32_t bits = x0 ^ x1;
  const float u = __uint_as_float((bits >> 9) | 0x3f800000u) - 1.0f;
  return u < 0.8f;
}

__device__ __forceinline__ uint32_t pack2(float x, float y) {
  U32H2 t; t.h = __builtin_amdgcn_cvt_pkrtz(x, y);
  return t.u;
}

__device__ __forceinline__ f16x2 as_h2(uint32_t u) {
  U32H2 t; t.u = u; return t.h;
}

#if __has_builtin(__builtin_amdgcn_fdot2)
__device__ __forceinline__ float dot2acc(float a, uint32_t q, uint32_t k) {
  return __builtin_amdgcn_fdot2(as_h2(q), as_h2(k), a, false);
}
#else
__device__ __forceinline__ float dot2acc(float a, uint32_t q, uint32_t k) {
  const f16x2 qh = as_h2(q), kh = as_h2(k);
  a = fmaf((float)qh[0], (float)kh[0], a);
  return fmaf((float)qh[1], (float)kh[1], a);
}
#endif

// 64-elem f16 dot, 4 accumulators (chain length 8), q from SGPRs
__device__ __forceinline__ float dot64(const uint32_t* qs, const uint32_t* kv) {
  float a0 = 0.f, a1 = 0.f, a2 = 0.f, a3 = 0.f;
#pragma unroll
  for (int d = 0; d < 8; ++d) {
    a0 = dot2acc(a0, qs[4 * d + 0], kv[4 * d + 0]);
    a1 = dot2acc(a1, qs[4 * d + 1], kv[4 * d + 1]);
    a2 = dot2acc(a2, qs[4 * d + 2], kv[4 * d + 2]);
    a3 = dot2acc(a3, qs[4 * d + 3], kv[4 * d + 3]);
  }
  return (a0 + a1) + (a2 + a3);
}

// ---- pre-pass: fp32 -> packed f16 for Q and K (1 MB into d_ws) ----
__global__ __launch_bounds__(NTH)
void cvt_kernel(const float* __restrict__ Q, const float* __restrict__ K,
                uint32_t* __restrict__ W) {
  const int i = blockIdx.x * NTH + threadIdx.x;          // 0..131071
  const float2 qf = reinterpret_cast<const float2*>(Q)[i];
  W[i] = pack2(qf.x, qf.y);
  const float2 kf = reinterpret_cast<const float2*>(K)[i];
  W[QH_U32 + i] = pack2(kf.x, kf.y);
}

__global__ __launch_bounds__(NTH)
void attn_kernel(const uint32_t* __restrict__ W, float* __restrict__ O) {
  __shared__ float redM[2][4], redS[2][4];

  const int tid = threadIdx.x;
  const int wv  = tid >> 6, ln = tid & 63;
  const int g   = blockIdx.x & 511;
  const int b   = blockIdx.x >> 9;
  const int rowL = g;            // 0..511
  const int rowH = 1023 - g;     // 512..1023

  // ---- q rows -> SGPRs (block-uniform; readfirstlane forces scalar regs) ----
  const uint32_t* Qb = W + (size_t)b * (TT * 32);
  uint32_t qL[32], qH[32];
#pragma unroll
  for (int d = 0; d < 32; ++d) {
    qL[d] = __builtin_amdgcn_readfirstlane(Qb[(size_t)rowL * 32 + d]);
    qH[d] = __builtin_amdgcn_readfirstlane(Qb[(size_t)rowH * 32 + d]);
  }

  const uint4* K4 = reinterpret_cast<const uint4*>(W + QH_U32) + (size_t)b * TT * 8;
  const float scale = 0.125f;   // 64^-0.5

  // sc[0][i] -> rowL, sc[1][i] -> rowH at key j = tid + 256*i
  float sc[2][4];
#pragma unroll
  for (int i = 0; i < 4; ++i) { sc[0][i] = NEG_INF; sc[1][i] = NEG_INF; }

#pragma unroll
  for (int ii = 0; ii < 2; ++ii) {     // pairs (0,1), (2,3): 2-deep prefetch
    const int j0 = tid + 512 * ii;
    const int j1 = j0 + 256;
    const bool v0 = (j0 <= rowH);
    const bool v1 = (j1 <= rowH);
    uint32_t kv0[32], kv1[32];
    if (v0) {
      const uint4* kb = K4 + (size_t)j0 * 8;
#pragma unroll
      for (int d4 = 0; d4 < 8; ++d4)
        *reinterpret_cast<uint4*>(&kv0[4 * d4]) = kb[d4];
    }
    if (v1) {
      const uint4* kb = K4 + (size_t)j1 * 8;
#pragma unroll
      for (int d4 = 0; d4 < 8; ++d4)
        *reinterpret_cast<uint4*>(&kv1[4 * d4]) = kb[d4];
    }
    if (v0) {
      sc[1][2 * ii] = dot64(qH, kv0) * scale;
      if (j0 <= rowL) sc[0][2 * ii] = dot64(qL, kv0) * scale;
    }
    if (v1) {
      sc[1][2 * ii + 1] = dot64(qH, kv1) * scale;
      if (j1 <= rowL) sc[0][2 * ii + 1] = dot64(qL, kv1) * scale;
    }
  }

  // ======================= softmax: row max ==============================
  float pm[2];
#pragma unroll
  for (int r = 0; r < 2; ++r)
    pm[r] = fmaxf(fmaxf(sc[r][0], sc[r][1]), fmaxf(sc[r][2], sc[r][3]));
#pragma unroll
  for (int off = 32; off; off >>= 1)
#pragma unroll
    for (int r = 0; r < 2; ++r) pm[r] = fmaxf(pm[r], __shfl_xor(pm[r], off));
  if (ln == 0) { redM[0][wv] = pm[0]; redM[1][wv] = pm[1]; }
  __syncthreads();
  float m[2];
#pragma unroll
  for (int r = 0; r < 2; ++r)
    m[r] = fmaxf(fmaxf(redM[r][0], redM[r][1]), fmaxf(redM[r][2], redM[r][3]));

  // ======================= exp + row sum =================================
  float ps[2];
#pragma unroll
  for (int r = 0; r < 2; ++r) {
    float s0 = 0.f;
#pragma unroll
    for (int i = 0; i < 4; ++i) {
      const float e = __expf(sc[r][i] - m[r]);   // exp(-inf) -> 0 for masked
      sc[r][i] = e;
      s0 += e;
    }
    ps[r] = s0;
  }
#pragma unroll
  for (int off = 32; off; off >>= 1)
#pragma unroll
    for (int r = 0; r < 2; ++r) ps[r] += __shfl_xor(ps[r], off);
  if (ln == 0) { redS[0][wv] = ps[0]; redS[1][wv] = ps[1]; }
  __syncthreads();
  float rs[2];
#pragma unroll
  for (int r = 0; r < 2; ++r)
    rs[r] = 1.25f / (redS[r][0] + redS[r][1] + redS[r][2] + redS[r][3]);

  // ============ write probs with deterministic dropout, coalesced ========
#pragma unroll
  for (int r = 0; r < 2; ++r) {
    const int row = (r == 0) ? rowL : rowH;
    const float scv = rs[r];
    const size_t base = ((size_t)b * TT + row) * TT;
#pragma unroll
    for (int i = 0; i < 4; ++i) {
      const int j = tid + 256 * i;
      float v = 0.f;
      if (j <= row)
        v = keep_at((uint32_t)(base + j)) ? sc[r][i] * scv : 0.f;
      O[base + j] = v;                 // zeros clear the poison
    }
  }
}

extern "C" void kernel_launch(void* const* d_in, const int* in_sizes, int n_in,
                              void* d_out, int out_size, void* d_ws, size_t ws_size,
                              hipStream_t stream) {
  const float* q = (const float*)d_in[0];
  const float* k = (const float*)d_in[1];
  float* out = (float*)d_out;
  uint32_t* w = (uint32_t*)d_ws;      // needs 2*QH_U32*4 = 1 MB
  cvt_kernel<<<dim3(QH_U32 / NTH), NTH, 0, stream>>>(q, k, w);
  attn_kernel<<<dim3(BB * 512), NTH, 0, stream>>>(w, out);
}

// Round 8
// 31.927 us; speedup vs baseline: 3.2076x; 1.2496x over previous
//
#include <hip/hip_runtime.h>
#include <hip/hip_fp16.h>
#include <stdint.h>

// B=4, T=1024, D=64 causal attention probs + deterministic JAX dropout.
// cvt pre-pass: Q,K fp32 -> packed f16 in d_ws (row-major, 128 B per row).
// attn: block g owns mirror row pair {g, 1023-g}. COALESCED K staging:
// 8 lanes cooperate per K row (lane l owns 16-B chunk o=l&7); one
// global_load_dwordx4 per wave-iter covers 8 rows at consecutive addresses
// (fixes the TA scattered-line serialization that bound R4-R7).
#define TT   1024
#define BB   4
#define NTH  256
#define NEG_INF (-3.4e38f)
#define QH_U32 (BB * TT * 32)   // Q as half2 words; Kh follows at same size

typedef __fp16 f16x2 __attribute__((ext_vector_type(2)));
union U32H2 { uint32_t u; f16x2 h; };

__device__ __forceinline__ uint32_t rotl32(uint32_t x, int d) {
  return (x << d) | (x >> (32 - d));
}

// JAX partitionable threefry (key(42)): (o0,o1)=tf2x32((0,42),(0,i));
// bits=o0^o1; u=bitcast((bits>>9)|0x3f800000)-1; keep = u<0.8   [verified R1]
__device__ __forceinline__ bool keep_at(uint32_t i) {
  uint32_t x0 = 0u, x1 = i;
  const uint32_t ks0 = 0u, ks1 = 42u;
  const uint32_t ks2 = 0x1BD11BDAu ^ ks0 ^ ks1;
  x0 += ks0; x1 += ks1;
#define R4(a,b,c,d)                              \
  x0 += x1; x1 = rotl32(x1,(a)); x1 ^= x0;       \
  x0 += x1; x1 = rotl32(x1,(b)); x1 ^= x0;       \
  x0 += x1; x1 = rotl32(x1,(c)); x1 ^= x0;       \
  x0 += x1; x1 = rotl32(x1,(d)); x1 ^= x0;
  R4(13,15,26,6)   x0 += ks1; x1 += ks2 + 1u;
  R4(17,29,16,24)  x0 += ks2; x1 += ks0 + 2u;
  R4(13,15,26,6)   x0 += ks0; x1 += ks1 + 3u;
  R4(17,29,16,24)  x0 += ks1; x1 += ks2 + 4u;
  R4(13,15,26,6)   x0 += ks2; x1 += ks0 + 5u;
#undef R4
  const uint32_t bits = x0 ^ x1;
  const float u = __uint_as_float((bits >> 9) | 0x3f800000u) - 1.0f;
  return u < 0.8f;
}

__device__ __forceinline__ uint32_t pack2(float x, float y) {
  U32H2 t; t.h = __builtin_amdgcn_cvt_pkrtz(x, y);
  return t.u;
}

__device__ __forceinline__ f16x2 as_h2(uint32_t u) {
  U32H2 t; t.u = u; return t.h;
}

#if __has_builtin(__builtin_amdgcn_fdot2)
__device__ __forceinline__ float dot2acc(float a, uint32_t q, uint32_t k) {
  return __builtin_amdgcn_fdot2(as_h2(q), as_h2(k), a, false);
}
#else
__device__ __forceinline__ float dot2acc(float a, uint32_t q, uint32_t k) {
  const f16x2 qh = as_h2(q), kh = as_h2(k);
  a = fmaf((float)qh[0], (float)kh[0], a);
  return fmaf((float)qh[1], (float)kh[1], a);
}
#endif

// partial dot of lane's 16-B chunks (8 f16 each)
__device__ __forceinline__ float dot16B(uint4 q, uint4 k) {
  float a = 0.f;
  a = dot2acc(a, q.x, k.x);
  a = dot2acc(a, q.y, k.y);
  a = dot2acc(a, q.z, k.z);
  a = dot2acc(a, q.w, k.w);
  return a;
}

// sum over the 8-lane chunk group (lanes differing in bits 0..2)
__device__ __forceinline__ float reduce8(float a) {
  a += __shfl_xor(a, 1);
  a += __shfl_xor(a, 2);
  a += __shfl_xor(a, 4);
  return a;
}

// ---- pre-pass: fp32 -> packed f16 for Q and K (1 MB into d_ws) ----
__global__ __launch_bounds__(NTH)
void cvt_kernel(const float* __restrict__ Q, const float* __restrict__ K,
                uint32_t* __restrict__ W) {
  const int i = blockIdx.x * NTH + threadIdx.x;          // 0..131071
  const float2 qf = reinterpret_cast<const float2*>(Q)[i];
  W[i] = pack2(qf.x, qf.y);
  const float2 kf = reinterpret_cast<const float2*>(K)[i];
  W[QH_U32 + i] = pack2(kf.x, kf.y);
}

__global__ __launch_bounds__(NTH)
void attn_kernel(const uint32_t* __restrict__ W, float* __restrict__ O) {
  __shared__ float scS[2][TT];        // raw scores (8 KB)
  __shared__ float redM[2][4], redS[2][4];

  const int tid = threadIdx.x;
  const int wv  = tid >> 6, ln = tid & 63;
  const int o   = ln & 7;             // 16-B chunk within a row
  const int rg  = ln >> 3;            // row-in-group 0..7
  const int g   = blockIdx.x & 511;
  const int b   = blockIdx.x >> 9;
  const int rowL = g;                 // 0..511
  const int rowH = 1023 - g;          // 512..1023

  // init score rows to -inf (masked slots stay -inf -> exp -> 0)
  float* scFlat = &scS[0][0];
#pragma unroll
  for (int t = 0; t < 8; ++t) scFlat[tid + NTH * t] = NEG_INF;

  // lane-resident q chunks (iter-invariant): lane holds chunk o of each row
  const uint4* Qh4 = reinterpret_cast<const uint4*>(W) + (size_t)b * TT * 8;
  const uint4* K4  = reinterpret_cast<const uint4*>(W + QH_U32) + (size_t)b * TT * 8;
  const uint4 qwL = Qh4[(size_t)rowL * 8 + o];
  const uint4 qwH = Qh4[(size_t)rowH * 8 + o];

  __syncthreads();                    // scS init visible

  // main loop: wave wv iter c covers rows jb..jb+7, jb = 32c + 8wv.
  // One coalesced dwordx4 per iter: K4[jb*8 + ln] (1 KB consecutive).
  const int nC = (rowH - 8 * wv) / 32 + 1;   // wave-uniform trip count
  int jb = 8 * wv;
  uint4 kw = K4[(size_t)jb * 8 + ln];
  for (int c = 0; c < nC; ++c) {
    const int jbn = (c + 1 < nC) ? (jb + 32) : jb;      // clamped prefetch
    const uint4 kwN = K4[(size_t)jbn * 8 + ln];
    const int row = jb + rg;
    const float aH = reduce8(dot16B(qwH, kw));
    if (o == 0 && row <= rowH) scS[1][row] = aH * 0.125f;
    if (jb <= rowL) {                                   // wave-uniform
      const float aL = reduce8(dot16B(qwL, kw));
      if (o == 0 && row <= rowL) scS[0][row] = aL * 0.125f;
    }
    kw = kwN;
    jb += 32;
  }
  __syncthreads();

  // ---- phase B: softmax over scS; each thread owns j = tid + 256*i ----
  float e[2][4];
  float pm[2];
#pragma unroll
  for (int r = 0; r < 2; ++r) {
#pragma unroll
    for (int i = 0; i < 4; ++i) e[r][i] = scS[r][tid + 256 * i];
    pm[r] = fmaxf(fmaxf(e[r][0], e[r][1]), fmaxf(e[r][2], e[r][3]));
  }
#pragma unroll
  for (int off = 32; off; off >>= 1)
#pragma unroll
    for (int r = 0; r < 2; ++r) pm[r] = fmaxf(pm[r], __shfl_xor(pm[r], off));
  if (ln == 0) { redM[0][wv] = pm[0]; redM[1][wv] = pm[1]; }
  __syncthreads();
  float m[2], ps[2];
#pragma unroll
  for (int r = 0; r < 2; ++r) {
    m[r] = fmaxf(fmaxf(redM[r][0], redM[r][1]), fmaxf(redM[r][2], redM[r][3]));
    float s0 = 0.f;
#pragma unroll
    for (int i = 0; i < 4; ++i) {
      const float ev = __expf(e[r][i] - m[r]);   // exp(-inf) -> 0 for masked
      e[r][i] = ev;
      s0 += ev;
    }
    ps[r] = s0;
  }
#pragma unroll
  for (int off = 32; off; off >>= 1)
#pragma unroll
    for (int r = 0; r < 2; ++r) ps[r] += __shfl_xor(ps[r], off);
  if (ln == 0) { redS[0][wv] = ps[0]; redS[1][wv] = ps[1]; }
  __syncthreads();
  float rs[2];
#pragma unroll
  for (int r = 0; r < 2; ++r)
    rs[r] = 1.25f / (redS[r][0] + redS[r][1] + redS[r][2] + redS[r][3]);

  // ---- epilogue: probs * deterministic dropout, coalesced stores ----
#pragma unroll
  for (int r = 0; r < 2; ++r) {
    const int row = (r == 0) ? rowL : rowH;
    const float scv = rs[r];
    const size_t base = ((size_t)b * TT + row) * TT;
#pragma unroll
    for (int i = 0; i < 4; ++i) {
      const int j = tid + 256 * i;
      float v = 0.f;
      if (j <= row)
        v = keep_at((uint32_t)(base + j)) ? e[r][i] * scv : 0.f;
      O[base + j] = v;                 // zeros clear the poison
    }
  }
}

extern "C" void kernel_launch(void* const* d_in, const int* in_sizes, int n_in,
                              void* d_out, int out_size, void* d_ws, size_t ws_size,
                              hipStream_t stream) {
  const float* q = (const float*)d_in[0];
  const float* k = (const float*)d_in[1];
  float* out = (float*)d_out;
  uint32_t* w = (uint32_t*)d_ws;      // needs 2*QH_U32*4 = 1 MB
  cvt_kernel<<<dim3(QH_U32 / NTH), NTH, 0, stream>>>(q, k, w);
  attn_kernel<<<dim3(BB * 512), NTH, 0, stream>>>(w, out);
}

// Round 9
// 29.789 us; speedup vs baseline: 3.4378x; 1.0718x over previous
//
#include <hip/hip_runtime.h>
#include <hip/hip_fp16.h>
#include <stdint.h>

// B=4, T=1024, D=64 causal attention probs + deterministic JAX dropout.
// cvt pre-pass: Q,K fp32 -> packed f16 in d_ws (128 B per row).
// attn: block g owns 2 mirror pairs {2g,2g+1,1022-2g,1023-2g} (R=4 rows,
// ~2049 dots/block uniform). 8 lanes cooperate per K row; one coalesced
// dwordx4 per wave-iter serves all 4 q-rows. 8-lane dot reduction via VALU
// DPP (quad_perm/row_half_mirror) instead of shfl -> no LDS-pipe traffic.
#define TT   1024
#define BB   4
#define NTH  256
#define NEG_INF (-3.4e38f)
#define QH_U32 (BB * TT * 32)   // Q as half2 words; Kh follows at same size

typedef __fp16 f16x2 __attribute__((ext_vector_type(2)));
union U32H2 { uint32_t u; f16x2 h; };

__device__ __forceinline__ uint32_t rotl32(uint32_t x, int d) {
  return (x << d) | (x >> (32 - d));
}

// JAX partitionable threefry (key(42)): (o0,o1)=tf2x32((0,42),(0,i));
// bits=o0^o1; u=bitcast((bits>>9)|0x3f800000)-1; keep = u<0.8   [verified R1]
__device__ __forceinline__ bool keep_at(uint32_t i) {
  uint32_t x0 = 0u, x1 = i;
  const uint32_t ks0 = 0u, ks1 = 42u;
  const uint32_t ks2 = 0x1BD11BDAu ^ ks0 ^ ks1;
  x0 += ks0; x1 += ks1;
#define R4(a,b,c,d)                              \
  x0 += x1; x1 = rotl32(x1,(a)); x1 ^= x0;       \
  x0 += x1; x1 = rotl32(x1,(b)); x1 ^= x0;       \
  x0 += x1; x1 = rotl32(x1,(c)); x1 ^= x0;       \
  x0 += x1; x1 = rotl32(x1,(d)); x1 ^= x0;
  R4(13,15,26,6)   x0 += ks1; x1 += ks2 + 1u;
  R4(17,29,16,24)  x0 += ks2; x1 += ks0 + 2u;
  R4(13,15,26,6)   x0 += ks0; x1 += ks1 + 3u;
  R4(17,29,16,24)  x0 += ks1; x1 += ks2 + 4u;
  R4(13,15,26,6)   x0 += ks2; x1 += ks0 + 5u;
#undef R4
  const uint32_t bits = x0 ^ x1;
  const float u = __uint_as_float((bits >> 9) | 0x3f800000u) - 1.0f;
  return u < 0.8f;
}

__device__ __forceinline__ uint32_t pack2(float x, float y) {
  U32H2 t; t.h = __builtin_amdgcn_cvt_pkrtz(x, y);
  return t.u;
}

__device__ __forceinline__ f16x2 as_h2(uint32_t u) {
  U32H2 t; t.u = u; return t.h;
}

#if __has_builtin(__builtin_amdgcn_fdot2)
__device__ __forceinline__ float dot2acc(float a, uint32_t q, uint32_t k) {
  return __builtin_amdgcn_fdot2(as_h2(q), as_h2(k), a, false);
}
#else
__device__ __forceinline__ float dot2acc(float a, uint32_t q, uint32_t k) {
  const f16x2 qh = as_h2(q), kh = as_h2(k);
  a = fmaf((float)qh[0], (float)kh[0], a);
  return fmaf((float)qh[1], (float)kh[1], a);
}
#endif

// partial dot of lane's 16-B chunks (8 f16 each)
__device__ __forceinline__ float dot16B(uint4 q, uint4 k) {
  float a = 0.f;
  a = dot2acc(a, q.x, k.x);
  a = dot2acc(a, q.y, k.y);
  a = dot2acc(a, q.z, k.z);
  a = dot2acc(a, q.w, k.w);
  return a;
}

// VALU DPP add: x + x[lane ^ pattern]  (no LDS pipe)
template <int CTRL>
__device__ __forceinline__ float add_dpp(float x) {
  const int s =
      __builtin_amdgcn_update_dpp(0, __float_as_int(x), CTRL, 0xF, 0xF, true);
  return x + __int_as_float(s);
}

// sum over the 8-lane chunk group (xor1, xor2, xor4) — same tree as shfl
__device__ __forceinline__ float reduce8(float a) {
  a = add_dpp<0xB1>(a);    // quad_perm [1,0,3,2]  : lane ^ 1
  a = add_dpp<0x4E>(a);    // quad_perm [2,3,0,1]  : lane ^ 2
  a = add_dpp<0x141>(a);   // row_half_mirror      : lane ^ 7 (quad-uniform -> ^4)
  return a;
}

// ---- pre-pass: fp32 -> packed f16 for Q and K (1 MB into d_ws) ----
__global__ __launch_bounds__(NTH)
void cvt_kernel(const float* __restrict__ Q, const float* __restrict__ K,
                uint32_t* __restrict__ W) {
  const int i = blockIdx.x * NTH + threadIdx.x;          // 0..131071
  const float2 qf = reinterpret_cast<const float2*>(Q)[i];
  W[i] = pack2(qf.x, qf.y);
  const float2 kf = reinterpret_cast<const float2*>(K)[i];
  W[QH_U32 + i] = pack2(kf.x, kf.y);
}

__global__ __launch_bounds__(NTH)
void attn_kernel(const uint32_t* __restrict__ W, float* __restrict__ O) {
  __shared__ float scS[4][TT];        // raw scores (16 KB)
  __shared__ float redM[4][4], redS[4][4];

  const int tid = threadIdx.x;
  const int wv  = tid >> 6, ln = tid & 63;
  const int o   = ln & 7;             // 16-B chunk within a row
  const int rg  = ln >> 3;            // row-in-group 0..7
  const int g   = blockIdx.x & 255;
  const int b   = blockIdx.x >> 8;
  int rowA[4];
  rowA[0] = 2 * g;                    // 0..510
  rowA[1] = 2 * g + 1;                // 1..511
  rowA[2] = 1022 - 2 * g;             // 512..1022
  rowA[3] = 1023 - 2 * g;             // 513..1023

  // init score rows to -inf (masked slots stay -inf -> exp -> 0)
  float* scFlat = &scS[0][0];
#pragma unroll
  for (int t = 0; t < 16; ++t) scFlat[tid + NTH * t] = NEG_INF;

  // lane-resident q chunks (iter-invariant): lane holds chunk o of each row
  const uint4* Qh4 = reinterpret_cast<const uint4*>(W) + (size_t)b * TT * 8;
  const uint4* K4  = reinterpret_cast<const uint4*>(W + QH_U32) + (size_t)b * TT * 8;
  uint4 qw[4];
#pragma unroll
  for (int t = 0; t < 4; ++t) qw[t] = Qh4[(size_t)rowA[t] * 8 + o];

  __syncthreads();                    // scS init visible

  // main loop: wave wv iter c covers K rows jb..jb+7, jb = 32c + 8wv.
  // One coalesced dwordx4 per iter (1 KB consecutive), reused by 4 q-rows.
  const int rowMax = rowA[3];
  const int nC = (rowMax - 8 * wv) / 32 + 1;   // wave-uniform trip count
  int jb = 8 * wv;
  uint4 kw = K4[(size_t)jb * 8 + ln];
  for (int c = 0; c < nC; ++c) {
    const int jbn = (c + 1 < nC) ? (jb + 32) : jb;      // clamped prefetch
    const uint4 kwN = K4[(size_t)jbn * 8 + ln];
    const int row = jb + rg;
#pragma unroll
    for (int t = 0; t < 4; ++t) {
      if (jb <= rowA[t]) {                              // wave-uniform
        const float a = reduce8(dot16B(qw[t], kw));
        if (o == 0 && row <= rowA[t]) scS[t][row] = a * 0.125f;
      }
    }
    kw = kwN;
    jb += 32;
  }
  __syncthreads();

  // ---- phase B: softmax over scS; each thread owns j = tid + 256*i ----
  float e[4][4], pm[4];
#pragma unroll
  for (int r = 0; r < 4; ++r) {
#pragma unroll
    for (int i = 0; i < 4; ++i) e[r][i] = scS[r][tid + 256 * i];
    pm[r] = fmaxf(fmaxf(e[r][0], e[r][1]), fmaxf(e[r][2], e[r][3]));
  }
#pragma unroll
  for (int off = 32; off; off >>= 1)
#pragma unroll
    for (int r = 0; r < 4; ++r) pm[r] = fmaxf(pm[r], __shfl_xor(pm[r], off));
  if (ln == 0) {
#pragma unroll
    for (int r = 0; r < 4; ++r) redM[r][wv] = pm[r];
  }
  __syncthreads();
  float m[4], ps[4];
#pragma unroll
  for (int r = 0; r < 4; ++r) {
    m[r] = fmaxf(fmaxf(redM[r][0], redM[r][1]), fmaxf(redM[r][2], redM[r][3]));
    float s0 = 0.f;
#pragma unroll
    for (int i = 0; i < 4; ++i) {
      const float ev = __expf(e[r][i] - m[r]);   // exp(-inf) -> 0 for masked
      e[r][i] = ev;
      s0 += ev;
    }
    ps[r] = s0;
  }
#pragma unroll
  for (int off = 32; off; off >>= 1)
#pragma unroll
    for (int r = 0; r < 4; ++r) ps[r] += __shfl_xor(ps[r], off);
  if (ln == 0) {
#pragma unroll
    for (int r = 0; r < 4; ++r) redS[r][wv] = ps[r];
  }
  __syncthreads();
  float rs[4];
#pragma unroll
  for (int r = 0; r < 4; ++r)
    rs[r] = 1.25f / (redS[r][0] + redS[r][1] + redS[r][2] + redS[r][3]);

  // ---- epilogue: probs * deterministic dropout, coalesced stores ----
#pragma unroll
  for (int r = 0; r < 4; ++r) {
    const int row = rowA[r];
    const float scv = rs[r];
    const size_t base = ((size_t)b * TT + row) * TT;
#pragma unroll
    for (int i = 0; i < 4; ++i) {
      const int j = tid + 256 * i;
      float v = 0.f;
      if (j <= row)
        v = keep_at((uint32_t)(base + j)) ? e[r][i] * scv : 0.f;
      O[base + j] = v;                 // zeros clear the poison
    }
  }
}

extern "C" void kernel_launch(void* const* d_in, const int* in_sizes, int n_in,
                              void* d_out, int out_size, void* d_ws, size_t ws_size,
                              hipStream_t stream) {
  const float* q = (const float*)d_in[0];
  const float* k = (const float*)d_in[1];
  float* out = (float*)d_out;
  uint32_t* w = (uint32_t*)d_ws;      // needs 2*QH_U32*4 = 1 MB
  cvt_kernel<<<dim3(QH_U32 / NTH), NTH, 0, stream>>>(q, k, w);
  attn_kernel<<<dim3(BB * 256), NTH, 0, stream>>>(w, out);
}